// Round 2
// baseline (463.352 us; speedup 1.0000x reference)
//
#include <hip/hip_runtime.h>
#include <hip/hip_bf16.h>

#define NB_  4096   // B_ = B*NW windows
#define NG_  49
#define NC_  128
#define NH_  4
#define DH_  32
#define NN_  50     // NG+1
#define NIMG 64
#define NT_  3136
#define SCALE_ 0.17677669529663687f

// workspace layout (u16 units unless noted)
#define WT_LO_OFF 49152      // low-order (residual) weight frags
#define BM_OFF    98304      // combined bias+mask frags [wx][h][tile16][lane][4] bf16
#define SBUF_F    573440     // float offset: global-path scores [img][3136][4] f32

typedef unsigned short u16;
typedef unsigned int   u32;
typedef __attribute__((ext_vector_type(8))) short bf16x8;   // 8 bf16 (4 VGPRs)
typedef __attribute__((ext_vector_type(4))) float f32x4;    // MFMA acc

__device__ __forceinline__ float b2f(u16 u) {
    union { u32 i; float f; } v; v.i = ((u32)u) << 16; return v.f;
}
__device__ __forceinline__ u16 f2b(float f) {
    union { float f; u32 i; } v; v.f = f;
    u32 x = v.i;
    return (u16)((x + 0x7fffu + ((x >> 16) & 1u)) >> 16);
}
__device__ __forceinline__ u32 pk2(float a, float b) {   // 2xf32 -> packed bf16x2 (RNE)
    union { __hip_bfloat162 h2; u32 u; } v;
    v.h2 = __float22bfloat162_rn(make_float2(a, b));
    return v.u;
}

// ---------------- pre-pass: weight frags (hi/lo, q pre-scaled) + bias+mask frags ----------------
extern "C" __global__ __launch_bounds__(256)
void prep_kernel(const float* __restrict__ Wq, const float* __restrict__ Wkv,
                 const float* __restrict__ btab, const int* __restrict__ ridx,
                 const float* __restrict__ mask, u16* __restrict__ ws)
{
    __shared__ int   ridxS[NG_ * NN_];
    __shared__ float btabS[169 * NH_];
    const int t = threadIdx.x, b = blockIdx.x;
    if (b < 24) {
        // weight fragment packing: tile tn=b (16 cols of [q|k|v] 384), kt = K-tile
        const int tn = b, kt = t >> 6, lane = t & 63;
        const int j  = tn * 16 + (lane & 15);          // output col 0..383
        const int k0 = kt * 32 + (lane >> 4) * 8;      // K base for this lane
        const float qs = (j < 128) ? SCALE_ : 1.f;     // fold q scale into weights
        u32 hi[4], lo[4];
        #pragma unroll
        for (int p = 0; p < 4; ++p) {
            const int k = k0 + 2 * p;
            float w0 = ((j < 128) ? Wq[(size_t)k * 128 + j]       : Wkv[(size_t)k * 256 + (j - 128)]) * qs;
            float w1 = ((j < 128) ? Wq[(size_t)(k + 1) * 128 + j] : Wkv[(size_t)(k + 1) * 256 + (j - 128)]) * qs;
            u16 h0 = f2b(w0), h1 = f2b(w1);
            hi[p] = (u32)h0 | ((u32)h1 << 16);
            lo[p] = (u32)f2b(w0 - b2f(h0)) | ((u32)f2b(w1 - b2f(h1)) << 16);
        }
        const size_t fo = ((size_t)(tn * 4 + kt) * 64 + lane) * 8;
        *(uint4*)(ws + fo)             = make_uint4(hi[0], hi[1], hi[2], hi[3]);
        *(uint4*)(ws + WT_LO_OFF + fo) = make_uint4(lo[0], lo[1], lo[2], lo[3]);
    } else {
        // bias+mask frags, one block per wx, in exact attention-load order
        const int wx = b - 24;
        for (int i = t; i < NG_ * NN_; i += 256) ridxS[i] = ridx[i];
        for (int i = t; i < 169 * NH_; i += 256) btabS[i] = btab[i];
        __syncthreads();
        for (int i = t; i < NH_ * 16 * 64; i += 256) {
            const int lane = i & 63, tile = (i >> 6) & 15, h = i >> 10;
            const int n  = 16 * (tile >> 2) + (lane & 15);   // q row
            const int m0 = 16 * (tile & 3) + 4 * (lane >> 4);// k col base
            u16 vv[4];
            #pragma unroll
            for (int e = 0; e < 4; ++e) {
                const int m = m0 + e;
                float val = -1e30f;
                if (n < NG_ && m < NN_)
                    val = btabS[ridxS[n * NN_ + m] * NH_ + h] + mask[((size_t)wx * NG_ + n) * NN_ + m];
                vv[e] = f2b(val);
            }
            u32* dst = (u32*)(ws + BM_OFF + ((size_t)((wx * NH_ + h) * 16 + tile) * 64 + lane) * 4);
            dst[0] = (u32)vv[0] | ((u32)vv[1] << 16);
            dst[1] = (u32)vv[2] | ((u32)vv[3] << 16);
        }
    }
}

// ---------------- main kernel ----------------
struct WinShared {              // 48 KiB
    u16 q[64][128];             // scaled q, XOR-swizzled
    u16 k[64][128];
    u16 buf[64 * 128];          // xc during projection-load, then vT[128][64]
};
struct GlobShared {             // ~8 KiB
    float qa[NH_][DH_];
    float xavgS[NC_];
    float u[NH_][NC_];
    float cst[NH_];
    float smax[NH_];
    float ssum[NH_];
    float red[256];
    float wpart[2][NH_][NC_];
};
union SMem { WinShared w; GlobShared g; };

extern "C" __global__ __launch_bounds__(256, 4)
void wa2_kernel(const float* __restrict__ x, const float* __restrict__ xtotal,
                const float* __restrict__ xavg,
                const float* __restrict__ Wq, const float* __restrict__ bq,
                const float* __restrict__ Wkv, const float* __restrict__ bkv,
                float* __restrict__ out, u16* __restrict__ ws)
{
    __shared__ SMem sm;
    const int t = threadIdx.x;
    const int blk = blockIdx.x;

    if (blk >= NIMG) {
        // ======================= window path (MFMA) =======================
        WinShared& S = sm.w;
        const int wb   = blk - NIMG;
        const int img  = wb >> 6;
        const int widx = wb & 63;
        const int lane = t & 63, wv = t >> 6;
        const int l15  = lane & 15, g = lane >> 4;

        // ---- stage x_c as bf16 into buf (swizzled) ----
        {
            u16* xc = S.buf;
            const float2* xr = (const float2*)(x + (size_t)wb * (NG_ * NC_));
            for (int i = t; i < NG_ * 64; i += 256) {
                const int row = i >> 6, cp = i & 63;
                float2 xv = xr[i];
                *(u32*)&xc[row * 128 + ((2 * cp) ^ ((row & 7) << 3))] = pk2(xv.x, xv.y);
            }
            if (t < 64) {
                float2 av = ((const float2*)(xavg + (size_t)img * NC_))[t];
                *(u32*)&xc[49 * 128 + ((2 * t) ^ 8)] = pk2(av.x, av.y);
            }
            for (int i = t; i < 14 * 64; i += 256) {
                const int row = 50 + (i >> 6), cp = i & 63;
                *(u32*)&xc[row * 128 + ((2 * cp) ^ ((row & 7) << 3))] = 0u;
            }
        }
        __syncthreads();

        const int sw = (l15 & 7) << 3;

        // ---- A-frags to registers; xc then dead -> buf becomes vT ----
        bf16x8 a[4][4];
        #pragma unroll
        for (int tm = 0; tm < 4; ++tm)
            #pragma unroll
            for (int kt = 0; kt < 4; ++kt)
                a[tm][kt] = *(const bf16x8*)&S.buf[(16 * tm + l15) * 128 + ((32 * kt + 8 * g) ^ sw)];
        __syncthreads();

        // ---- projection: [64x128] @ [128x384]; bias in C-init, hi+lo weights ----
        {
            u16* vT = S.buf;   // [128][64]: vT[c*64 + (row ^ ((c&7)<<3))]
            for (int i = 0; i < 6; ++i) {
                const int tn = 6 * wv + i;
                const int jc = tn * 16 + l15;
                const float bias = (jc < 128) ? bq[jc] * SCALE_ : bkv[jc - 128];
                f32x4 acc[4];
                #pragma unroll
                for (int tm = 0; tm < 4; ++tm) acc[tm] = (f32x4){bias, bias, bias, bias};
                #pragma unroll
                for (int kt = 0; kt < 4; ++kt) {
                    const size_t fo = ((size_t)(tn * 4 + kt) * 64 + lane) * 8;
                    bf16x8 bh = *(const bf16x8*)(ws + fo);
                    bf16x8 bl = *(const bf16x8*)(ws + WT_LO_OFF + fo);
                    #pragma unroll
                    for (int tm = 0; tm < 4; ++tm) {
                        acc[tm] = __builtin_amdgcn_mfma_f32_16x16x32_bf16(a[tm][kt], bh, acc[tm], 0, 0, 0);
                        acc[tm] = __builtin_amdgcn_mfma_f32_16x16x32_bf16(a[tm][kt], bl, acc[tm], 0, 0, 0);
                    }
                }
                #pragma unroll
                for (int tm = 0; tm < 4; ++tm) {
                    #pragma unroll
                    for (int rp = 0; rp < 2; ++rp) {
                        const int r0 = 16 * tm + 4 * g + 2 * rp;
                        const u32 p = pk2(acc[tm][2 * rp], acc[tm][2 * rp + 1]);
                        if (jc < 128) {
                            S.q[r0][jc ^ ((r0 & 7) << 3)]           = (u16)p;
                            S.q[r0 + 1][jc ^ (((r0 + 1) & 7) << 3)] = (u16)(p >> 16);
                        } else if (jc < 256) {
                            const int c = jc - 128;
                            S.k[r0][c ^ ((r0 & 7) << 3)]           = (u16)p;
                            S.k[r0 + 1][c ^ (((r0 + 1) & 7) << 3)] = (u16)(p >> 16);
                        } else {
                            const int c = jc - 256, swc = (c & 7) << 3;
                            vT[c * 64 + (r0 ^ swc)]       = (u16)p;
                            vT[c * 64 + ((r0 + 1) ^ swc)] = (u16)(p >> 16);
                        }
                    }
                }
            }
        }
        __syncthreads();

        // ---- attention: wave = head; bm as MFMA C-input; in-register softmax ----
        {
            const int h = wv;
            const u16* vT = S.buf;
            bf16x8 ka[4], qb[4];
            #pragma unroll
            for (int tk = 0; tk < 4; ++tk)
                ka[tk] = *(const bf16x8*)&S.k[16 * tk + l15][(32 * h + 8 * g) ^ sw];
            #pragma unroll
            for (int tq = 0; tq < 4; ++tq)
                qb[tq] = *(const bf16x8*)&S.q[16 * tq + l15][(32 * h + 8 * g) ^ sw];

            // S^T = K @ Q^T + bm : lane holds kcol = 16tk+4g+r, qrow = 16tq+l15
            const u16* bmb = ws + BM_OFF + (size_t)(widx * NH_ + h) * 4096;
            f32x4 s[4][4];   // [tk][tq]
            #pragma unroll
            for (int tq = 0; tq < 4; ++tq)
                #pragma unroll
                for (int tk = 0; tk < 4; ++tk) {
                    uint2 bm = *(const uint2*)(bmb + ((size_t)(tq * 4 + tk) * 64 + lane) * 4);
                    f32x4 c0;
                    c0[0] = b2f((u16)bm.x); c0[1] = b2f((u16)(bm.x >> 16));
                    c0[2] = b2f((u16)bm.y); c0[3] = b2f((u16)(bm.y >> 16));
                    s[tk][tq] = __builtin_amdgcn_mfma_f32_16x16x32_bf16(ka[tk], qb[tq], c0, 0, 0, 0);
                }

            // softmax over kcol per qrow: 15 in-lane + 2 shfl_xor
            float inv[4];
            #pragma unroll
            for (int tq = 0; tq < 4; ++tq) {
                float m = s[0][tq][0];
                #pragma unroll
                for (int tk = 0; tk < 4; ++tk)
                    #pragma unroll
                    for (int r = 0; r < 4; ++r) m = fmaxf(m, s[tk][tq][r]);
                m = fmaxf(m, __shfl_xor(m, 16));
                m = fmaxf(m, __shfl_xor(m, 32));
                float sum = 0.f;
                #pragma unroll
                for (int tk = 0; tk < 4; ++tk)
                    #pragma unroll
                    for (int r = 0; r < 4; ++r) {
                        float e = __expf(s[tk][tq][r] - m);
                        s[tk][tq][r] = e;
                        sum += e;
                    }
                sum += __shfl_xor(sum, 16);
                sum += __shfl_xor(sum, 32);
                inv[tq] = 1.f / sum;
            }

            // pack P in-register into AV A-frags; k-perm mirrored on V-frag reads
            bf16x8 pa[4][2];   // [tq][kt]; slot (g,e) <-> kcol 32kt+16(e>>2)+4g+(e&3)
            #pragma unroll
            for (int tq = 0; tq < 4; ++tq) {
                const float iv = inv[tq];
                #pragma unroll
                for (int kt = 0; kt < 2; ++kt) {
                    union { u32 u[4]; bf16x8 v; } P;
                    P.u[0] = pk2(s[2 * kt][tq][0] * iv, s[2 * kt][tq][1] * iv);
                    P.u[1] = pk2(s[2 * kt][tq][2] * iv, s[2 * kt][tq][3] * iv);
                    P.u[2] = pk2(s[2 * kt + 1][tq][0] * iv, s[2 * kt + 1][tq][1] * iv);
                    P.u[3] = pk2(s[2 * kt + 1][tq][2] * iv, s[2 * kt + 1][tq][3] * iv);
                    pa[tq][kt] = P.v;
                }
            }
            bf16x8 vb[2][2];   // [kt][tn] V B-frags, same k-perm
            #pragma unroll
            for (int tn = 0; tn < 2; ++tn) {
                const int c = 32 * h + 16 * tn + l15;
                const int swv = (c & 7) << 3;
                #pragma unroll
                for (int kt = 0; kt < 2; ++kt) {
                    union { uint2 u2[2]; bf16x8 v; } B;
                    B.u2[0] = *(const uint2*)&vT[c * 64 + ((32 * kt + 4 * g) ^ swv)];
                    B.u2[1] = *(const uint2*)&vT[c * 64 + ((32 * kt + 16 + 4 * g) ^ swv)];
                    vb[kt][tn] = B.v;
                }
            }
            #pragma unroll
            for (int tq = 0; tq < 4; ++tq)
                #pragma unroll
                for (int tn = 0; tn < 2; ++tn) {
                    f32x4 acc = {0.f, 0.f, 0.f, 0.f};
                    acc = __builtin_amdgcn_mfma_f32_16x16x32_bf16(pa[tq][0], vb[0][tn], acc, 0, 0, 0);
                    acc = __builtin_amdgcn_mfma_f32_16x16x32_bf16(pa[tq][1], vb[1][tn], acc, 0, 0, 0);
                    #pragma unroll
                    for (int r = 0; r < 4; ++r) {
                        const int row = 16 * tq + 4 * g + r;
                        if (row < NG_)
                            out[(size_t)wb * (NG_ * NC_) + (size_t)row * NC_ + 32 * h + 16 * tn + l15] = acc[r];
                    }
                }
        }
    } else {
        // ======================= global path (scores in workspace) =======================
        GlobShared& S = sm.g;
        const int img = blk;
        float* sb = (float*)ws + SBUF_F + (size_t)img * (NT_ * NH_);

        if (t < NC_) S.xavgS[t] = xavg[img * NC_ + t];
        __syncthreads();

        if (t < NC_) {
            const int h = t >> 5, jj = t & 31;
            float acc = bq[h * DH_ + jj];
            for (int c = 0; c < NC_; ++c) acc += S.xavgS[c] * Wq[c * NC_ + h * DH_ + jj];
            S.qa[h][jj] = acc;
        }
        __syncthreads();

        if (t < NC_) {
            const int c = t;
            #pragma unroll
            for (int h = 0; h < NH_; ++h) {
                float acc = 0.f;
                const float* wr = Wkv + (size_t)c * (2 * NC_) + h * DH_;
                #pragma unroll
                for (int jj = 0; jj < DH_; ++jj) acc += wr[jj] * S.qa[h][jj];
                S.u[h][c] = acc;
            }
        } else if (t < NC_ + NH_) {
            const int h = t - NC_;
            float acc = 0.f;
            for (int jj = 0; jj < DH_; ++jj) acc += S.qa[h][jj] * bkv[h * DH_ + jj];
            S.cst[h] = acc;
        }
        __syncthreads();

        float lmax0 = -1e30f, lmax1 = -1e30f, lmax2 = -1e30f, lmax3 = -1e30f;
        for (int m = t; m < NT_; m += 256) {
            const float* xr = xtotal + (size_t)(img * NT_ + m) * NC_;
            float a0 = S.cst[0], a1 = S.cst[1], a2 = S.cst[2], a3 = S.cst[3];
            for (int c = 0; c < NC_; ++c) {
                float xv = xr[c];
                a0 += xv * S.u[0][c];
                a1 += xv * S.u[1][c];
                a2 += xv * S.u[2][c];
                a3 += xv * S.u[3][c];
            }
            *(float4*)&sb[m * NH_] = make_float4(a0, a1, a2, a3);
            lmax0 = fmaxf(lmax0, a0); lmax1 = fmaxf(lmax1, a1);
            lmax2 = fmaxf(lmax2, a2); lmax3 = fmaxf(lmax3, a3);
        }
        float lm[NH_] = {lmax0, lmax1, lmax2, lmax3};
        for (int h = 0; h < NH_; ++h) {
            __syncthreads();
            S.red[t] = lm[h];
            __syncthreads();
            for (int off = 128; off > 0; off >>= 1) {
                if (t < off) S.red[t] = fmaxf(S.red[t], S.red[t + off]);
                __syncthreads();
            }
            if (t == 0) S.smax[h] = S.red[0];
        }
        __syncthreads();

        float ls[NH_] = {0.f, 0.f, 0.f, 0.f};
        for (int m = t; m < NT_; m += 256) {
            float4 sv = *(const float4*)&sb[m * NH_];
            sv.x = __expf(sv.x - S.smax[0]); ls[0] += sv.x;
            sv.y = __expf(sv.y - S.smax[1]); ls[1] += sv.y;
            sv.z = __expf(sv.z - S.smax[2]); ls[2] += sv.z;
            sv.w = __expf(sv.w - S.smax[3]); ls[3] += sv.w;
            *(float4*)&sb[m * NH_] = sv;
        }
        for (int h = 0; h < NH_; ++h) {
            __syncthreads();
            S.red[t] = ls[h];
            __syncthreads();
            for (int off = 128; off > 0; off >>= 1) {
                if (t < off) S.red[t] += S.red[t + off];
                __syncthreads();
            }
            if (t == 0) S.ssum[h] = S.red[0];
        }
        __syncthreads();

        {
            const int c = t & 127, half = t >> 7;
            float a0 = 0.f, a1 = 0.f, a2 = 0.f, a3 = 0.f;
            const int m0 = half * (NT_ / 2), m1 = m0 + NT_ / 2;
            for (int m = m0; m < m1; ++m) {
                float xv = xtotal[(size_t)(img * NT_ + m) * NC_ + c];
                float4 e4 = *(const float4*)&sb[m * NH_];
                a0 += e4.x * xv; a1 += e4.y * xv;
                a2 += e4.z * xv; a3 += e4.w * xv;
            }
            S.wpart[half][0][c] = a0; S.wpart[half][1][c] = a1;
            S.wpart[half][2][c] = a2; S.wpart[half][3][c] = a3;
        }
        __syncthreads();

        if (t < NC_) {
            const int h = t >> 5;
            const float winv = 1.f / S.ssum[h];
            float acc = bkv[NC_ + t];
            for (int c = 0; c < NC_; ++c) {
                float wv = (S.wpart[0][h][c] + S.wpart[1][h][c]) * winv;
                acc += wv * Wkv[(size_t)c * (2 * NC_) + NC_ + t];
            }
            out[(size_t)NB_ * (NG_ * NC_) + img * NC_ + t] = acc;
        }
    }
}

extern "C" void kernel_launch(void* const* d_in, const int* in_sizes, int n_in,
                              void* d_out, int out_size, void* d_ws, size_t ws_size,
                              hipStream_t stream) {
    const float* x      = (const float*)d_in[0];
    const float* xtotal = (const float*)d_in[1];
    const float* xavg   = (const float*)d_in[2];
    const float* mask   = (const float*)d_in[3];
    const float* Wq     = (const float*)d_in[4];
    const float* bq     = (const float*)d_in[5];
    const float* Wkv    = (const float*)d_in[6];
    const float* bkv    = (const float*)d_in[7];
    const float* btab   = (const float*)d_in[8];
    const int*   ridx   = (const int*)d_in[9];
    float* outp = (float*)d_out;
    u16*   ws   = (u16*)d_ws;
    (void)in_sizes; (void)n_in; (void)out_size; (void)ws_size;

    // prep: 24 weight-frag blocks + 64 bias+mask blocks (LDS-staged, coalesced)
    prep_kernel<<<24 + 64, 256, 0, stream>>>(Wq, Wkv, btab, ridx, mask, ws);
    // global blocks first (long pole, overlaps the window wave)
    wa2_kernel<<<NB_ + NIMG, 256, 0, stream>>>(x, xtotal, xavg, Wq, bq,
                                               Wkv, bkv, outp, ws);
}

// Round 3
// 442.528 us; speedup vs baseline: 1.0471x; 1.0471x over previous
//
#include <hip/hip_runtime.h>
#include <hip/hip_bf16.h>

#define NB_  4096   // B_ = B*NW windows
#define NG_  49
#define NC_  128
#define NH_  4
#define DH_  32
#define NN_  50     // NG+1
#define NIMG 64
#define NT_  3136
#define NCHK 8      // chunk blocks per image (global path)
#define CROWS 392   // NT_/NCHK
#define SCALE_ 0.17677669529663687f

// workspace layout (u16 units unless noted)
#define WT_LO_OFF 49152      // low-order (residual) weight frags
#define BM_OFF    98304      // combined bias+mask frags [wx][h][tile16][lane][4] bf16
// float-offset area (starts at u16 1146880 = byte 2293760)
#define FBASE  573440
#define U_F    (FBASE)            // [img][4][128] u vectors
#define CST_F  (FBASE + 32768)    // [img][4]
#define WACC_F (FBASE + 33024)    // [img][4][128] w accumulators
#define SUM_F  (FBASE + 65792)    // [img][4] exp-sums
#define CNT_F  (FBASE + 66048)    // [img] int fan-in counters

typedef unsigned short u16;
typedef unsigned int   u32;
typedef __attribute__((ext_vector_type(8))) short bf16x8;   // 8 bf16 (4 VGPRs)
typedef __attribute__((ext_vector_type(4))) float f32x4;    // MFMA acc

__device__ __forceinline__ float b2f(u16 u) {
    union { u32 i; float f; } v; v.i = ((u32)u) << 16; return v.f;
}
__device__ __forceinline__ u16 f2b(float f) {
    union { float f; u32 i; } v; v.f = f;
    u32 x = v.i;
    return (u16)((x + 0x7fffu + ((x >> 16) & 1u)) >> 16);
}
__device__ __forceinline__ u32 pk2(float a, float b) {   // 2xf32 -> packed bf16x2 (RNE)
    union { __hip_bfloat162 h2; u32 u; } v;
    v.h2 = __float22bfloat162_rn(make_float2(a, b));
    return v.u;
}

// ---------------- pre-pass: weight frags + bias+mask frags + per-image u/cst + zeroing ----------------
extern "C" __global__ __launch_bounds__(256)
void prep_kernel(const float* __restrict__ Wq, const float* __restrict__ Wkv,
                 const float* __restrict__ btab, const int* __restrict__ ridx,
                 const float* __restrict__ mask, const float* __restrict__ xavg,
                 const float* __restrict__ bq, const float* __restrict__ bkv,
                 u16* __restrict__ ws)
{
    __shared__ int   ridxS[NG_ * NN_];
    __shared__ float btabS[169 * NH_];
    __shared__ float xavgS[NC_];
    __shared__ float qaS[NC_];
    const int t = threadIdx.x, b = blockIdx.x;
    if (b < 24) {
        // weight fragment packing: tile tn=b (16 cols of [q|k|v] 384), kt = K-tile
        const int tn = b, kt = t >> 6, lane = t & 63;
        const int j  = tn * 16 + (lane & 15);          // output col 0..383
        const int k0 = kt * 32 + (lane >> 4) * 8;      // K base for this lane
        const float qs = (j < 128) ? SCALE_ : 1.f;     // fold q scale into weights
        u32 hi[4], lo[4];
        #pragma unroll
        for (int p = 0; p < 4; ++p) {
            const int k = k0 + 2 * p;
            float w0 = ((j < 128) ? Wq[(size_t)k * 128 + j]       : Wkv[(size_t)k * 256 + (j - 128)]) * qs;
            float w1 = ((j < 128) ? Wq[(size_t)(k + 1) * 128 + j] : Wkv[(size_t)(k + 1) * 256 + (j - 128)]) * qs;
            u16 h0 = f2b(w0), h1 = f2b(w1);
            hi[p] = (u32)h0 | ((u32)h1 << 16);
            lo[p] = (u32)f2b(w0 - b2f(h0)) | ((u32)f2b(w1 - b2f(h1)) << 16);
        }
        const size_t fo = ((size_t)(tn * 4 + kt) * 64 + lane) * 8;
        *(uint4*)(ws + fo)             = make_uint4(hi[0], hi[1], hi[2], hi[3]);
        *(uint4*)(ws + WT_LO_OFF + fo) = make_uint4(lo[0], lo[1], lo[2], lo[3]);
    } else if (b < 88) {
        // bias+mask frags, one block per wx, in exact attention-load order
        const int wx = b - 24;
        for (int i = t; i < NG_ * NN_; i += 256) ridxS[i] = ridx[i];
        for (int i = t; i < 169 * NH_; i += 256) btabS[i] = btab[i];
        __syncthreads();
        for (int i = t; i < NH_ * 16 * 64; i += 256) {
            const int lane = i & 63, tile = (i >> 6) & 15, h = i >> 10;
            const int n  = 16 * (tile >> 2) + (lane & 15);   // q row
            const int m0 = 16 * (tile & 3) + 4 * (lane >> 4);// k col base
            u16 vv[4];
            #pragma unroll
            for (int e = 0; e < 4; ++e) {
                const int m = m0 + e;
                float val = -1e30f;
                if (n < NG_ && m < NN_)
                    val = btabS[ridxS[n * NN_ + m] * NH_ + h] + mask[((size_t)wx * NG_ + n) * NN_ + m];
                vv[e] = f2b(val);
            }
            u32* dst = (u32*)(ws + BM_OFF + ((size_t)((wx * NH_ + h) * 16 + tile) * 64 + lane) * 4);
            dst[0] = (u32)vv[0] | ((u32)vv[1] << 16);
            dst[1] = (u32)vv[2] | ((u32)vv[3] << 16);
        }
    } else {
        // per-image: qa -> u, cst; zero w/sum/cnt accumulators
        const int img = b - 88;
        float* wsF = (float*)ws;
        if (t < NC_) xavgS[t] = xavg[img * NC_ + t];
        __syncthreads();
        if (t < NC_) {
            float acc = bq[t];
            for (int c = 0; c < NC_; ++c) acc += xavgS[c] * Wq[c * NC_ + t];
            qaS[t] = acc;
        }
        __syncthreads();
        if (t < NC_) {
            const int c = t;
            const float* wr = Wkv + (size_t)c * 256;
            #pragma unroll
            for (int h = 0; h < NH_; ++h) {
                float acc = 0.f;
                #pragma unroll
                for (int j = 0; j < 32; ++j) acc += wr[h * 32 + j] * qaS[h * 32 + j];
                wsF[U_F + img * 512 + h * 128 + c] = acc;
            }
            #pragma unroll
            for (int h = 0; h < NH_; ++h) wsF[WACC_F + img * 512 + h * 128 + t] = 0.f;
        } else if (t < NC_ + NH_) {
            const int h = t - NC_;
            float acc = 0.f;
            for (int j = 0; j < 32; ++j) acc += qaS[h * 32 + j] * bkv[h * 32 + j];
            wsF[CST_F + img * 4 + h] = acc;
            wsF[SUM_F + img * 4 + h] = 0.f;
        } else if (t == NC_ + NH_) {
            ((int*)wsF)[CNT_F + img] = 0;
        }
    }
}

// ---------------- main kernel ----------------
struct WinShared {              // 48 KiB
    u16 q[64][128];             // scaled q, XOR-swizzled
    u16 k[64][128];
    u16 buf[64 * 128];          // xc during projection-load, then vT[128][64]
};
struct ChunkShared {            // ~8.1 KiB
    float waccS[4][4][128];     // [wave][h][c]
    float esumS[4][4];
    float sumS[4];
    int   flagS;
};
union SMem { WinShared w; ChunkShared c; };

extern "C" __global__ __launch_bounds__(256, 4)
void wa2_kernel(const float* __restrict__ x, const float* __restrict__ xtotal,
                const float* __restrict__ xavg,
                const float* __restrict__ Wq, const float* __restrict__ bq,
                const float* __restrict__ Wkv, const float* __restrict__ bkv,
                float* __restrict__ out, u16* __restrict__ ws)
{
    __shared__ SMem sm;
    const int t = threadIdx.x;
    const int blk = blockIdx.x;
    const int lane = t & 63, wv = t >> 6;

    if (blk >= NIMG * NCHK) {
        // ======================= window path (MFMA) =======================
        WinShared& S = sm.w;
        const int wb   = blk - NIMG * NCHK;
        const int img  = wb >> 6;
        const int widx = wb & 63;
        const int l15  = lane & 15, g = lane >> 4;

        // ---- stage x_c as bf16 into buf (swizzled) ----
        {
            u16* xc = S.buf;
            const float2* xr = (const float2*)(x + (size_t)wb * (NG_ * NC_));
            for (int i = t; i < NG_ * 64; i += 256) {
                const int row = i >> 6, cp = i & 63;
                float2 xv = xr[i];
                *(u32*)&xc[row * 128 + ((2 * cp) ^ ((row & 7) << 3))] = pk2(xv.x, xv.y);
            }
            if (t < 64) {
                float2 av = ((const float2*)(xavg + (size_t)img * NC_))[t];
                *(u32*)&xc[49 * 128 + ((2 * t) ^ 8)] = pk2(av.x, av.y);
            }
            for (int i = t; i < 14 * 64; i += 256) {
                const int row = 50 + (i >> 6), cp = i & 63;
                *(u32*)&xc[row * 128 + ((2 * cp) ^ ((row & 7) << 3))] = 0u;
            }
        }
        __syncthreads();

        const int sw = (l15 & 7) << 3;

        // ---- A-frags to registers; xc then dead -> buf becomes vT ----
        bf16x8 a[4][4];
        #pragma unroll
        for (int tm = 0; tm < 4; ++tm)
            #pragma unroll
            for (int kt = 0; kt < 4; ++kt)
                a[tm][kt] = *(const bf16x8*)&S.buf[(16 * tm + l15) * 128 + ((32 * kt + 8 * g) ^ sw)];
        __syncthreads();

        // ---- projection: [64x128] @ [128x384]; bias in C-init, hi+lo weights ----
        {
            u16* vT = S.buf;   // [128][64]: vT[c*64 + (row ^ ((c&7)<<3))]
            for (int i = 0; i < 6; ++i) {
                const int tn = 6 * wv + i;
                const int jc = tn * 16 + l15;
                const float bias = (jc < 128) ? bq[jc] * SCALE_ : bkv[jc - 128];
                f32x4 acc[4];
                #pragma unroll
                for (int tm = 0; tm < 4; ++tm) acc[tm] = (f32x4){bias, bias, bias, bias};
                #pragma unroll
                for (int kt = 0; kt < 4; ++kt) {
                    const size_t fo = ((size_t)(tn * 4 + kt) * 64 + lane) * 8;
                    bf16x8 bh = *(const bf16x8*)(ws + fo);
                    bf16x8 bl = *(const bf16x8*)(ws + WT_LO_OFF + fo);
                    #pragma unroll
                    for (int tm = 0; tm < 4; ++tm) {
                        acc[tm] = __builtin_amdgcn_mfma_f32_16x16x32_bf16(a[tm][kt], bh, acc[tm], 0, 0, 0);
                        acc[tm] = __builtin_amdgcn_mfma_f32_16x16x32_bf16(a[tm][kt], bl, acc[tm], 0, 0, 0);
                    }
                }
                #pragma unroll
                for (int tm = 0; tm < 4; ++tm) {
                    #pragma unroll
                    for (int rp = 0; rp < 2; ++rp) {
                        const int r0 = 16 * tm + 4 * g + 2 * rp;
                        const u32 p = pk2(acc[tm][2 * rp], acc[tm][2 * rp + 1]);
                        if (jc < 128) {
                            S.q[r0][jc ^ ((r0 & 7) << 3)]           = (u16)p;
                            S.q[r0 + 1][jc ^ (((r0 + 1) & 7) << 3)] = (u16)(p >> 16);
                        } else if (jc < 256) {
                            const int c = jc - 128;
                            S.k[r0][c ^ ((r0 & 7) << 3)]           = (u16)p;
                            S.k[r0 + 1][c ^ (((r0 + 1) & 7) << 3)] = (u16)(p >> 16);
                        } else {
                            const int c = jc - 256, swc = (c & 7) << 3;
                            vT[c * 64 + (r0 ^ swc)]       = (u16)p;
                            vT[c * 64 + ((r0 + 1) ^ swc)] = (u16)(p >> 16);
                        }
                    }
                }
            }
        }
        __syncthreads();

        // ---- attention: wave = head; bm as MFMA C-input; in-register softmax ----
        {
            const int h = wv;
            const u16* vT = S.buf;
            bf16x8 ka[4], qb[4];
            #pragma unroll
            for (int tk = 0; tk < 4; ++tk)
                ka[tk] = *(const bf16x8*)&S.k[16 * tk + l15][(32 * h + 8 * g) ^ sw];
            #pragma unroll
            for (int tq = 0; tq < 4; ++tq)
                qb[tq] = *(const bf16x8*)&S.q[16 * tq + l15][(32 * h + 8 * g) ^ sw];

            // S^T = K @ Q^T + bm : lane holds kcol = 16tk+4g+r, qrow = 16tq+l15
            const u16* bmb = ws + BM_OFF + (size_t)(widx * NH_ + h) * 4096;
            f32x4 s[4][4];   // [tk][tq]
            #pragma unroll
            for (int tq = 0; tq < 4; ++tq)
                #pragma unroll
                for (int tk = 0; tk < 4; ++tk) {
                    uint2 bm = *(const uint2*)(bmb + ((size_t)(tq * 4 + tk) * 64 + lane) * 4);
                    f32x4 c0;
                    c0[0] = b2f((u16)bm.x); c0[1] = b2f((u16)(bm.x >> 16));
                    c0[2] = b2f((u16)bm.y); c0[3] = b2f((u16)(bm.y >> 16));
                    s[tk][tq] = __builtin_amdgcn_mfma_f32_16x16x32_bf16(ka[tk], qb[tq], c0, 0, 0, 0);
                }

            // softmax over kcol per qrow: 15 in-lane + 2 shfl_xor
            float inv[4];
            #pragma unroll
            for (int tq = 0; tq < 4; ++tq) {
                float m = s[0][tq][0];
                #pragma unroll
                for (int tk = 0; tk < 4; ++tk)
                    #pragma unroll
                    for (int r = 0; r < 4; ++r) m = fmaxf(m, s[tk][tq][r]);
                m = fmaxf(m, __shfl_xor(m, 16));
                m = fmaxf(m, __shfl_xor(m, 32));
                float sum = 0.f;
                #pragma unroll
                for (int tk = 0; tk < 4; ++tk)
                    #pragma unroll
                    for (int r = 0; r < 4; ++r) {
                        float e = __expf(s[tk][tq][r] - m);
                        s[tk][tq][r] = e;
                        sum += e;
                    }
                sum += __shfl_xor(sum, 16);
                sum += __shfl_xor(sum, 32);
                inv[tq] = 1.f / sum;
            }

            // pack P in-register into AV A-frags; k-perm mirrored on V-frag reads
            bf16x8 pa[4][2];   // [tq][kt]; slot (g,e) <-> kcol 32kt+16(e>>2)+4g+(e&3)
            #pragma unroll
            for (int tq = 0; tq < 4; ++tq) {
                const float iv = inv[tq];
                #pragma unroll
                for (int kt = 0; kt < 2; ++kt) {
                    union { u32 u[4]; bf16x8 v; } P;
                    P.u[0] = pk2(s[2 * kt][tq][0] * iv, s[2 * kt][tq][1] * iv);
                    P.u[1] = pk2(s[2 * kt][tq][2] * iv, s[2 * kt][tq][3] * iv);
                    P.u[2] = pk2(s[2 * kt + 1][tq][0] * iv, s[2 * kt + 1][tq][1] * iv);
                    P.u[3] = pk2(s[2 * kt + 1][tq][2] * iv, s[2 * kt + 1][tq][3] * iv);
                    pa[tq][kt] = P.v;
                }
            }
            bf16x8 vb[2][2];   // [kt][tn] V B-frags, same k-perm
            #pragma unroll
            for (int tn = 0; tn < 2; ++tn) {
                const int c = 32 * h + 16 * tn + l15;
                const int swv = (c & 7) << 3;
                #pragma unroll
                for (int kt = 0; kt < 2; ++kt) {
                    union { uint2 u2[2]; bf16x8 v; } B;
                    B.u2[0] = *(const uint2*)&vT[c * 64 + ((32 * kt + 4 * g) ^ swv)];
                    B.u2[1] = *(const uint2*)&vT[c * 64 + ((32 * kt + 16 + 4 * g) ^ swv)];
                    vb[kt][tn] = B.v;
                }
            }
            #pragma unroll
            for (int tq = 0; tq < 4; ++tq)
                #pragma unroll
                for (int tn = 0; tn < 2; ++tn) {
                    f32x4 acc = {0.f, 0.f, 0.f, 0.f};
                    acc = __builtin_amdgcn_mfma_f32_16x16x32_bf16(pa[tq][0], vb[0][tn], acc, 0, 0, 0);
                    acc = __builtin_amdgcn_mfma_f32_16x16x32_bf16(pa[tq][1], vb[1][tn], acc, 0, 0, 0);
                    #pragma unroll
                    for (int r = 0; r < 4; ++r) {
                        const int row = 16 * tq + 4 * g + r;
                        if (row < NG_)
                            out[(size_t)wb * (NG_ * NC_) + (size_t)row * NC_ + 32 * h + 16 * tn + l15] = acc[r];
                    }
                }
        }
    } else {
        // ======================= global path: chunked one-pass softmax-accumulate =======================
        ChunkShared& S = sm.c;
        float* wsF = (float*)ws;
        const int img = blk >> 3, ch = blk & 7;
        const int c0 = (lane & 31) * 4, roff = lane >> 5;

        // u, cst into registers (fixed c-slice per lane)
        float4 uR[NH_]; float cstR[NH_];
        #pragma unroll
        for (int h = 0; h < NH_; ++h) {
            uR[h]  = *(const float4*)&wsF[U_F + img * 512 + h * 128 + c0];
            cstR[h] = wsF[CST_F + img * 4 + h];
        }

        float wacc[NH_][4] = {};
        float esum[NH_] = {0.f, 0.f, 0.f, 0.f};
        const float* xb = xtotal + ((size_t)img * NT_ + ch * CROWS) * NC_;
        for (int it = 0; it < CROWS / 8; ++it) {
            const int m = it * 8 + wv * 2 + roff;
            float4 xv = *(const float4*)&xb[(size_t)m * NC_ + c0];
            float s[NH_];
            #pragma unroll
            for (int h = 0; h < NH_; ++h)
                s[h] = xv.x * uR[h].x + xv.y * uR[h].y + xv.z * uR[h].z + xv.w * uR[h].w;
            #pragma unroll
            for (int off = 1; off < 32; off <<= 1) {
                #pragma unroll
                for (int h = 0; h < NH_; ++h) s[h] += __shfl_xor(s[h], off);
            }
            #pragma unroll
            for (int h = 0; h < NH_; ++h) {
                const float e = __expf(s[h] + cstR[h]);   // no max-shift: |s| <~ 35 << 87
                wacc[h][0] += e * xv.x; wacc[h][1] += e * xv.y;
                wacc[h][2] += e * xv.z; wacc[h][3] += e * xv.w;
                if ((lane & 31) == 0) esum[h] += e;
            }
        }

        // combine row-halves (lane ^ 32 shares the same c-slice)
        #pragma unroll
        for (int h = 0; h < NH_; ++h) {
            #pragma unroll
            for (int i = 0; i < 4; ++i) wacc[h][i] += __shfl_xor(wacc[h][i], 32);
            esum[h] += __shfl_xor(esum[h], 32);
        }
        if (lane < 32) {
            #pragma unroll
            for (int h = 0; h < NH_; ++h)
                #pragma unroll
                for (int i = 0; i < 4; ++i) S.waccS[wv][h][c0 + i] = wacc[h][i];
            if (lane == 0) {
                #pragma unroll
                for (int h = 0; h < NH_; ++h) S.esumS[wv][h] = esum[h];
            }
        }
        __syncthreads();
        if (t < NC_) {
            #pragma unroll
            for (int h = 0; h < NH_; ++h) {
                float v = S.waccS[0][h][t] + S.waccS[1][h][t] + S.waccS[2][h][t] + S.waccS[3][h][t];
                atomicAdd(&wsF[WACC_F + img * 512 + h * 128 + t], v);
            }
        } else if (t < NC_ + NH_) {
            const int h = t - NC_;
            atomicAdd(&wsF[SUM_F + img * 4 + h],
                      S.esumS[0][h] + S.esumS[1][h] + S.esumS[2][h] + S.esumS[3][h]);
        }
        __threadfence();
        __syncthreads();
        if (t == 0) S.flagS = atomicAdd(&((int*)wsF)[CNT_F + img], 1);
        __syncthreads();
        if (S.flagS == NCHK - 1) {
            // last chunk of this image: finish out_avg = (w/sum)@Wv + bv
            float* wS = &S.waccS[0][0][0];      // reuse (all waves past barrier)
            for (int i = t; i < 512; i += 256)
                wS[i] = atomicAdd(&wsF[WACC_F + img * 512 + i], 0.f);
            if (t < NH_) S.sumS[t] = atomicAdd(&wsF[SUM_F + img * 4 + t], 0.f);
            __syncthreads();
            if (t < NC_) {
                const int h = t >> 5;
                const float inv = 1.f / S.sumS[h];
                float acc = bkv[NC_ + t];
                for (int c = 0; c < NC_; ++c)
                    acc += (wS[h * 128 + c] * inv) * Wkv[(size_t)c * 256 + NC_ + t];
                out[(size_t)NB_ * (NG_ * NC_) + img * NC_ + t] = acc;
            }
        }
    }
}

extern "C" void kernel_launch(void* const* d_in, const int* in_sizes, int n_in,
                              void* d_out, int out_size, void* d_ws, size_t ws_size,
                              hipStream_t stream) {
    const float* x      = (const float*)d_in[0];
    const float* xtotal = (const float*)d_in[1];
    const float* xavg   = (const float*)d_in[2];
    const float* mask   = (const float*)d_in[3];
    const float* Wq     = (const float*)d_in[4];
    const float* bq     = (const float*)d_in[5];
    const float* Wkv    = (const float*)d_in[6];
    const float* bkv    = (const float*)d_in[7];
    const float* btab   = (const float*)d_in[8];
    const int*   ridx   = (const int*)d_in[9];
    float* outp = (float*)d_out;
    u16*   ws   = (u16*)d_ws;
    (void)in_sizes; (void)n_in; (void)out_size; (void)ws_size;

    // prep: 24 weight-frag + 64 bias+mask + 64 per-image (u/cst + accumulator zeroing)
    prep_kernel<<<152, 256, 0, stream>>>(Wq, Wkv, btab, ridx, mask, xavg, bq, bkv, ws);
    // chunk blocks first (they feed the fan-in epilogue), then 4096 window blocks
    wa2_kernel<<<NIMG * NCHK + NB_, 256, 0, stream>>>(x, xtotal, xavg, Wq, bq,
                                                      Wkv, bkv, outp, ws);
}

// Round 4
// 426.572 us; speedup vs baseline: 1.0862x; 1.0374x over previous
//
#include <hip/hip_runtime.h>
#include <hip/hip_bf16.h>

#define NB_  4096   // B_ = B*NW windows
#define NG_  49
#define NC_  128
#define NH_  4
#define DH_  32
#define NN_  50     // NG+1
#define NIMG 64
#define NT_  3136
#define NCHK 8      // chunk blocks per image (global path)
#define CROWS 392   // NT_/NCHK
#define SCALE_ 0.17677669529663687f

// workspace layout (u16 units unless noted)
// weight frags: fp = ((h*3+ty)*2+jt)*4+kt, ty in {q,k,v}; each frag 64 lanes x 8 u16
#define WT_LO_OFF 49152      // low-order (residual) weight frags
#define BM_OFF    98304      // combined bias+mask frags [wx][h][tile16][lane][4] bf16
// float-offset area
#define FBASE  573440
#define U_F    (FBASE)            // [img][4][128] u vectors
#define CST_F  (FBASE + 32768)    // [img][4]
#define WACC_F (FBASE + 33024)    // [img][4][128] w accumulators
#define SUM_F  (FBASE + 65792)    // [img][4] exp-sums
#define CNT_F  (FBASE + 66048)    // [img] int fan-in counters

typedef unsigned short u16;
typedef unsigned int   u32;
typedef __attribute__((ext_vector_type(8))) short bf16x8;   // 8 bf16 (4 VGPRs)
typedef __attribute__((ext_vector_type(4))) float f32x4;    // MFMA acc

__device__ __forceinline__ float b2f(u16 u) {
    union { u32 i; float f; } v; v.i = ((u32)u) << 16; return v.f;
}
__device__ __forceinline__ u16 f2b(float f) {
    union { float f; u32 i; } v; v.f = f;
    u32 x = v.i;
    return (u16)((x + 0x7fffu + ((x >> 16) & 1u)) >> 16);
}
__device__ __forceinline__ u32 pk2(float a, float b) {   // 2xf32 -> packed bf16x2 (RNE)
    union { __hip_bfloat162 h2; u32 u; } v;
    v.h2 = __float22bfloat162_rn(make_float2(a, b));
    return v.u;
}

// ---------------- pre-pass: weight frags + bias+mask frags + per-image u/cst + zeroing ----------------
extern "C" __global__ __launch_bounds__(256)
void prep_kernel(const float* __restrict__ Wq, const float* __restrict__ Wkv,
                 const float* __restrict__ btab, const int* __restrict__ ridx,
                 const float* __restrict__ mask, const float* __restrict__ xavg,
                 const float* __restrict__ bq, const float* __restrict__ bkv,
                 u16* __restrict__ ws)
{
    __shared__ int   ridxS[NG_ * NN_];
    __shared__ float btabS[169 * NH_];
    __shared__ float xavgS[NC_];
    __shared__ float qaS[NC_];
    const int t = threadIdx.x, b = blockIdx.x;
    if (b < 24) {
        // transposed weight frags: lane holds out-col j (l15), 8 contiguous in-chans at 32kt+8g
        const int fp  = b * 4 + (t >> 6);
        const int lane = t & 63, l15 = lane & 15, g = lane >> 4;
        const int kt = fp & 3, rest = fp >> 2, jt = rest & 1, hty = rest >> 1;
        const int ty = hty % 3, hh = hty / 3;
        const int jc = 32 * hh + 16 * jt + l15;
        const float* src; int stride; float qs = 1.f;
        if (ty == 0)      { src = Wq  + jc;       stride = NC_;     qs = SCALE_; }
        else if (ty == 1) { src = Wkv + jc;       stride = 2 * NC_; }
        else              { src = Wkv + NC_ + jc; stride = 2 * NC_; }
        const int c0 = 32 * kt + 8 * g;
        u32 hi[4], lo[4];
        #pragma unroll
        for (int p = 0; p < 4; ++p) {
            const int c = c0 + 2 * p;
            float w0 = src[(size_t)c * stride] * qs;
            float w1 = src[(size_t)(c + 1) * stride] * qs;
            u16 h0 = f2b(w0), h1 = f2b(w1);
            hi[p] = (u32)h0 | ((u32)h1 << 16);
            lo[p] = (u32)f2b(w0 - b2f(h0)) | ((u32)f2b(w1 - b2f(h1)) << 16);
        }
        const size_t fo = ((size_t)fp * 64 + lane) * 8;
        *(uint4*)(ws + fo)             = make_uint4(hi[0], hi[1], hi[2], hi[3]);
        *(uint4*)(ws + WT_LO_OFF + fo) = make_uint4(lo[0], lo[1], lo[2], lo[3]);
    } else if (b < 88) {
        // bias+mask frags, one block per wx, in exact attention-load order
        const int wx = b - 24;
        for (int i = t; i < NG_ * NN_; i += 256) ridxS[i] = ridx[i];
        for (int i = t; i < 169 * NH_; i += 256) btabS[i] = btab[i];
        __syncthreads();
        for (int i = t; i < NH_ * 16 * 64; i += 256) {
            const int lane = i & 63, tile = (i >> 6) & 15, h = i >> 10;
            const int n  = 16 * (tile >> 2) + (lane & 15);   // q row
            const int m0 = 16 * (tile & 3) + 4 * (lane >> 4);// k col base
            u16 vv[4];
            #pragma unroll
            for (int e = 0; e < 4; ++e) {
                const int m = m0 + e;
                float val = -1e30f;
                if (n < NG_ && m < NN_)
                    val = btabS[ridxS[n * NN_ + m] * NH_ + h] + mask[((size_t)wx * NG_ + n) * NN_ + m];
                vv[e] = f2b(val);
            }
            u32* dst = (u32*)(ws + BM_OFF + ((size_t)((wx * NH_ + h) * 16 + tile) * 64 + lane) * 4);
            dst[0] = (u32)vv[0] | ((u32)vv[1] << 16);
            dst[1] = (u32)vv[2] | ((u32)vv[3] << 16);
        }
    } else {
        // per-image: qa -> u, cst; zero w/sum/cnt accumulators
        const int img = b - 88;
        float* wsF = (float*)ws;
        if (t < NC_) xavgS[t] = xavg[img * NC_ + t];
        __syncthreads();
        if (t < NC_) {
            float acc = bq[t];
            for (int c = 0; c < NC_; ++c) acc += xavgS[c] * Wq[c * NC_ + t];
            qaS[t] = acc;
        }
        __syncthreads();
        if (t < NC_) {
            const int c = t;
            const float* wr = Wkv + (size_t)c * 256;
            #pragma unroll
            for (int h = 0; h < NH_; ++h) {
                float acc = 0.f;
                #pragma unroll
                for (int j = 0; j < 32; ++j) acc += wr[h * 32 + j] * qaS[h * 32 + j];
                wsF[U_F + img * 512 + h * 128 + c] = acc;
            }
            #pragma unroll
            for (int h = 0; h < NH_; ++h) wsF[WACC_F + img * 512 + h * 128 + t] = 0.f;
        } else if (t < NC_ + NH_) {
            const int h = t - NC_;
            float acc = 0.f;
            for (int j = 0; j < 32; ++j) acc += qaS[h * 32 + j] * bkv[h * 32 + j];
            wsF[CST_F + img * 4 + h] = acc;
            wsF[SUM_F + img * 4 + h] = 0.f;
        } else if (t == NC_ + NH_) {
            ((int*)wsF)[CNT_F + img] = 0;
        }
    }
}

// ---------------- main kernel ----------------
struct ChunkShared {            // ~8.2 KiB (window path uses NO LDS)
    float waccS[4][4][128];     // [wave][h][c]
    float esumS[4][4];
    float sumS[4];
    int   flagS;
};

extern "C" __global__ __launch_bounds__(256, 3)
void wa2_kernel(const float* __restrict__ x, const float* __restrict__ xtotal,
                const float* __restrict__ xavg,
                const float* __restrict__ Wq, const float* __restrict__ bq,
                const float* __restrict__ Wkv, const float* __restrict__ bkv,
                float* __restrict__ out, u16* __restrict__ ws)
{
    __shared__ ChunkShared smc;
    const int t = threadIdx.x;
    const int blk = blockIdx.x;
    const int lane = t & 63, wv = t >> 6;

    if (blk >= NIMG * NCHK) {
        // =========== window path: per-wave, LDS-free, barrier-free ===========
        const int wb   = blk - NIMG * NCHK;
        const int img  = wb >> 6;
        const int widx = wb & 63;
        const int h = wv, l15 = lane & 15, g = lane >> 4;

        // ---- x fragments straight from global (lane = row, 8 contiguous chans) ----
        bf16x8 xf[4][4];
        {
            const float* xbase = x + (size_t)wb * (NG_ * NC_);
            #pragma unroll
            for (int rt = 0; rt < 4; ++rt) {
                const int row = 16 * rt + l15;
                const float* rp = (row < NG_) ? (xbase + (size_t)row * NC_)
                                              : (xavg + (size_t)img * NC_);
                const bool vld = (row <= NG_);
                #pragma unroll
                for (int kt = 0; kt < 4; ++kt) {
                    float4 u0 = *(const float4*)(rp + 32 * kt + 8 * g);
                    float4 u1 = *(const float4*)(rp + 32 * kt + 8 * g + 4);
                    if (!vld) { u0 = make_float4(0.f,0.f,0.f,0.f); u1 = make_float4(0.f,0.f,0.f,0.f); }
                    union { u32 w[4]; bf16x8 v; } F;
                    F.w[0] = pk2(u0.x, u0.y); F.w[1] = pk2(u0.z, u0.w);
                    F.w[2] = pk2(u1.x, u1.y); F.w[3] = pk2(u1.z, u1.w);
                    xf[rt][kt] = F.v;
                }
            }
        }

        // ---- q,k: transposed projection mfma(A=W^T, B=x); acc lane=row, chans in regs ----
        bf16x8 qf[4], kf[4];
        #pragma unroll
        for (int ty = 0; ty < 2; ++ty) {
            f32x4 acc[2][4];
            #pragma unroll
            for (int jt = 0; jt < 2; ++jt) {
                f32x4 cin;
                #pragma unroll
                for (int r = 0; r < 4; ++r) {
                    const int j = 32 * h + 16 * jt + 4 * g + r;
                    cin[r] = (ty == 0) ? bq[j] * SCALE_ : bkv[j];
                }
                #pragma unroll
                for (int rt = 0; rt < 4; ++rt) acc[jt][rt] = cin;
            }
            #pragma unroll
            for (int kt = 0; kt < 4; ++kt) {
                const int fpb = ((h * 3 + ty) * 2) * 4 + kt;   // jt=0; jt=1 is +4
                const bf16x8 wh0 = *(const bf16x8*)(ws + ((size_t)fpb * 64 + lane) * 8);
                const bf16x8 wl0 = *(const bf16x8*)(ws + WT_LO_OFF + ((size_t)fpb * 64 + lane) * 8);
                const bf16x8 wh1 = *(const bf16x8*)(ws + ((size_t)(fpb + 4) * 64 + lane) * 8);
                const bf16x8 wl1 = *(const bf16x8*)(ws + WT_LO_OFF + ((size_t)(fpb + 4) * 64 + lane) * 8);
                #pragma unroll
                for (int rt = 0; rt < 4; ++rt) {
                    acc[0][rt] = __builtin_amdgcn_mfma_f32_16x16x32_bf16(wh0, xf[rt][kt], acc[0][rt], 0, 0, 0);
                    acc[0][rt] = __builtin_amdgcn_mfma_f32_16x16x32_bf16(wl0, xf[rt][kt], acc[0][rt], 0, 0, 0);
                    acc[1][rt] = __builtin_amdgcn_mfma_f32_16x16x32_bf16(wh1, xf[rt][kt], acc[1][rt], 0, 0, 0);
                    acc[1][rt] = __builtin_amdgcn_mfma_f32_16x16x32_bf16(wl1, xf[rt][kt], acc[1][rt], 0, 0, 0);
                }
            }
            // pack per row-tile: frag slot s=jt*4+r <-> chan 16jt+4g+r (shared sigma)
            #pragma unroll
            for (int rt = 0; rt < 4; ++rt) {
                union { u32 w[4]; bf16x8 v; } F;
                F.w[0] = pk2(acc[0][rt][0], acc[0][rt][1]);
                F.w[1] = pk2(acc[0][rt][2], acc[0][rt][3]);
                F.w[2] = pk2(acc[1][rt][0], acc[1][rt][1]);
                F.w[3] = pk2(acc[1][rt][2], acc[1][rt][3]);
                if (ty == 0) qf[rt] = F.v; else kf[rt] = F.v;
            }
        }

        // ---- v: plain projection mfma(A=x, B=Wv); acc lane=out-chan, rows in regs ----
        bf16x8 vbf[2][2];
        {
            f32x4 vacc[4][2];
            #pragma unroll
            for (int tn = 0; tn < 2; ++tn) {
                const float bv = bkv[NC_ + 32 * h + 16 * tn + l15];
                #pragma unroll
                for (int tm = 0; tm < 4; ++tm) vacc[tm][tn] = (f32x4){bv, bv, bv, bv};
            }
            #pragma unroll
            for (int kt = 0; kt < 4; ++kt) {
                const int fpb = ((h * 3 + 2) * 2) * 4 + kt;
                const bf16x8 wh0 = *(const bf16x8*)(ws + ((size_t)fpb * 64 + lane) * 8);
                const bf16x8 wl0 = *(const bf16x8*)(ws + WT_LO_OFF + ((size_t)fpb * 64 + lane) * 8);
                const bf16x8 wh1 = *(const bf16x8*)(ws + ((size_t)(fpb + 4) * 64 + lane) * 8);
                const bf16x8 wl1 = *(const bf16x8*)(ws + WT_LO_OFF + ((size_t)(fpb + 4) * 64 + lane) * 8);
                #pragma unroll
                for (int tm = 0; tm < 4; ++tm) {
                    vacc[tm][0] = __builtin_amdgcn_mfma_f32_16x16x32_bf16(xf[tm][kt], wh0, vacc[tm][0], 0, 0, 0);
                    vacc[tm][0] = __builtin_amdgcn_mfma_f32_16x16x32_bf16(xf[tm][kt], wl0, vacc[tm][0], 0, 0, 0);
                    vacc[tm][1] = __builtin_amdgcn_mfma_f32_16x16x32_bf16(xf[tm][kt], wh1, vacc[tm][1], 0, 0, 0);
                    vacc[tm][1] = __builtin_amdgcn_mfma_f32_16x16x32_bf16(xf[tm][kt], wl1, vacc[tm][1], 0, 0, 0);
                }
            }
            // pack PV B-frags: slot s <-> krow 32kt2+16(s>>2)+4g+(s&3) (shared tau with pa)
            #pragma unroll
            for (int kt2 = 0; kt2 < 2; ++kt2)
                #pragma unroll
                for (int tn = 0; tn < 2; ++tn) {
                    union { u32 w[4]; bf16x8 v; } F;
                    F.w[0] = pk2(vacc[2 * kt2][tn][0], vacc[2 * kt2][tn][1]);
                    F.w[1] = pk2(vacc[2 * kt2][tn][2], vacc[2 * kt2][tn][3]);
                    F.w[2] = pk2(vacc[2 * kt2 + 1][tn][0], vacc[2 * kt2 + 1][tn][1]);
                    F.w[3] = pk2(vacc[2 * kt2 + 1][tn][2], vacc[2 * kt2 + 1][tn][3]);
                    vbf[kt2][tn] = F.v;
                }
        }

        // ---- attention, fused per q-tile: QK^T (bm as C) -> softmax -> PV -> store ----
        const u16* bmb = ws + BM_OFF + (size_t)(widx * NH_ + h) * 4096;
        #pragma unroll
        for (int tq = 0; tq < 4; ++tq) {
            f32x4 s[4];
            #pragma unroll
            for (int tk = 0; tk < 4; ++tk) {
                uint2 bm = *(const uint2*)(bmb + ((size_t)(tq * 4 + tk) * 64 + lane) * 4);
                f32x4 c0;
                c0[0] = b2f((u16)bm.x); c0[1] = b2f((u16)(bm.x >> 16));
                c0[2] = b2f((u16)bm.y); c0[3] = b2f((u16)(bm.y >> 16));
                s[tk] = __builtin_amdgcn_mfma_f32_16x16x32_bf16(kf[tk], qf[tq], c0, 0, 0, 0);
            }
            float mx = s[0][0];
            #pragma unroll
            for (int tk = 0; tk < 4; ++tk)
                #pragma unroll
                for (int r = 0; r < 4; ++r) mx = fmaxf(mx, s[tk][r]);
            mx = fmaxf(mx, __shfl_xor(mx, 16));
            mx = fmaxf(mx, __shfl_xor(mx, 32));
            float sum = 0.f;
            #pragma unroll
            for (int tk = 0; tk < 4; ++tk)
                #pragma unroll
                for (int r = 0; r < 4; ++r) {
                    float e = __expf(s[tk][r] - mx);
                    s[tk][r] = e;
                    sum += e;
                }
            sum += __shfl_xor(sum, 16);
            sum += __shfl_xor(sum, 32);
            const float inv = 1.f / sum;

            bf16x8 pa[2];
            #pragma unroll
            for (int kt2 = 0; kt2 < 2; ++kt2) {
                union { u32 w[4]; bf16x8 v; } P;
                P.w[0] = pk2(s[2 * kt2][0] * inv, s[2 * kt2][1] * inv);
                P.w[1] = pk2(s[2 * kt2][2] * inv, s[2 * kt2][3] * inv);
                P.w[2] = pk2(s[2 * kt2 + 1][0] * inv, s[2 * kt2 + 1][1] * inv);
                P.w[3] = pk2(s[2 * kt2 + 1][2] * inv, s[2 * kt2 + 1][3] * inv);
                pa[kt2] = P.v;
            }
            #pragma unroll
            for (int tn = 0; tn < 2; ++tn) {
                f32x4 o = {0.f, 0.f, 0.f, 0.f};
                o = __builtin_amdgcn_mfma_f32_16x16x32_bf16(pa[0], vbf[0][tn], o, 0, 0, 0);
                o = __builtin_amdgcn_mfma_f32_16x16x32_bf16(pa[1], vbf[1][tn], o, 0, 0, 0);
                #pragma unroll
                for (int r = 0; r < 4; ++r) {
                    const int row = 16 * tq + 4 * g + r;
                    if (row < NG_)
                        out[(size_t)wb * (NG_ * NC_) + (size_t)row * NC_ + 32 * h + 16 * tn + l15] = o[r];
                }
            }
        }
    } else {
        // ======================= global path: chunked one-pass softmax-accumulate =======================
        ChunkShared& S = smc;
        float* wsF = (float*)ws;
        const int img = blk >> 3, ch = blk & 7;
        const int c0 = (lane & 31) * 4, roff = lane >> 5;

        // u, cst into registers (fixed c-slice per lane)
        float4 uR[NH_]; float cstR[NH_];
        #pragma unroll
        for (int h = 0; h < NH_; ++h) {
            uR[h]  = *(const float4*)&wsF[U_F + img * 512 + h * 128 + c0];
            cstR[h] = wsF[CST_F + img * 4 + h];
        }

        float wacc[NH_][4] = {};
        float esum[NH_] = {0.f, 0.f, 0.f, 0.f};
        const float* xb = xtotal + ((size_t)img * NT_ + ch * CROWS) * NC_;
        for (int it = 0; it < CROWS / 8; ++it) {
            const int m = it * 8 + wv * 2 + roff;
            float4 xv = *(const float4*)&xb[(size_t)m * NC_ + c0];
            float s[NH_];
            #pragma unroll
            for (int h = 0; h < NH_; ++h)
                s[h] = xv.x * uR[h].x + xv.y * uR[h].y + xv.z * uR[h].z + xv.w * uR[h].w;
            #pragma unroll
            for (int off = 1; off < 32; off <<= 1) {
                #pragma unroll
                for (int h = 0; h < NH_; ++h) s[h] += __shfl_xor(s[h], off);
            }
            #pragma unroll
            for (int h = 0; h < NH_; ++h) {
                const float e = __expf(s[h] + cstR[h]);   // no max-shift: |s| <~ 35 << 87
                wacc[h][0] += e * xv.x; wacc[h][1] += e * xv.y;
                wacc[h][2] += e * xv.z; wacc[h][3] += e * xv.w;
                if ((lane & 31) == 0) esum[h] += e;
            }
        }

        // combine row-halves (lane ^ 32 shares the same c-slice)
        #pragma unroll
        for (int h = 0; h < NH_; ++h) {
            #pragma unroll
            for (int i = 0; i < 4; ++i) wacc[h][i] += __shfl_xor(wacc[h][i], 32);
            esum[h] += __shfl_xor(esum[h], 32);
        }
        if (lane < 32) {
            #pragma unroll
            for (int h = 0; h < NH_; ++h)
                #pragma unroll
                for (int i = 0; i < 4; ++i) S.waccS[wv][h][c0 + i] = wacc[h][i];
            if (lane == 0) {
                #pragma unroll
                for (int h = 0; h < NH_; ++h) S.esumS[wv][h] = esum[h];
            }
        }
        __syncthreads();
        if (t < NC_) {
            #pragma unroll
            for (int h = 0; h < NH_; ++h) {
                float v = S.waccS[0][h][t] + S.waccS[1][h][t] + S.waccS[2][h][t] + S.waccS[3][h][t];
                atomicAdd(&wsF[WACC_F + img * 512 + h * 128 + t], v);
            }
        } else if (t < NC_ + NH_) {
            const int h = t - NC_;
            atomicAdd(&wsF[SUM_F + img * 4 + h],
                      S.esumS[0][h] + S.esumS[1][h] + S.esumS[2][h] + S.esumS[3][h]);
        }
        __threadfence();
        __syncthreads();
        if (t == 0) S.flagS = atomicAdd(&((int*)wsF)[CNT_F + img], 1);
        __syncthreads();
        if (S.flagS == NCHK - 1) {
            // last chunk of this image: finish out_avg = (w/sum)@Wv + bv
            float* wS = &S.waccS[0][0][0];      // reuse (all waves past barrier)
            for (int i = t; i < 512; i += 256)
                wS[i] = atomicAdd(&wsF[WACC_F + img * 512 + i], 0.f);
            if (t < NH_) S.sumS[t] = atomicAdd(&wsF[SUM_F + img * 4 + t], 0.f);
            __syncthreads();
            if (t < NC_) {
                const int h = t >> 5;
                const float inv = 1.f / S.sumS[h];
                float acc = bkv[NC_ + t];
                for (int c = 0; c < NC_; ++c)
                    acc += (wS[h * 128 + c] * inv) * Wkv[(size_t)c * 256 + NC_ + t];
                out[(size_t)NB_ * (NG_ * NC_) + img * NC_ + t] = acc;
            }
        }
    }
}

extern "C" void kernel_launch(void* const* d_in, const int* in_sizes, int n_in,
                              void* d_out, int out_size, void* d_ws, size_t ws_size,
                              hipStream_t stream) {
    const float* x      = (const float*)d_in[0];
    const float* xtotal = (const float*)d_in[1];
    const float* xavg   = (const float*)d_in[2];
    const float* mask   = (const float*)d_in[3];
    const float* Wq     = (const float*)d_in[4];
    const float* bq     = (const float*)d_in[5];
    const float* Wkv    = (const float*)d_in[6];
    const float* bkv    = (const float*)d_in[7];
    const float* btab   = (const float*)d_in[8];
    const int*   ridx   = (const int*)d_in[9];
    float* outp = (float*)d_out;
    u16*   ws   = (u16*)d_ws;
    (void)in_sizes; (void)n_in; (void)out_size; (void)ws_size;

    // prep: 24 weight-frag + 64 bias+mask + 64 per-image (u/cst + accumulator zeroing)
    prep_kernel<<<152, 256, 0, stream>>>(Wq, Wkv, btab, ridx, mask, xavg, bq, bkv, ws);
    // chunk blocks first (they feed the fan-in epilogue), then 4096 window blocks
    wa2_kernel<<<NIMG * NCHK + NB_, 256, 0, stream>>>(x, xtotal, xavg, Wq, bq,
                                                      Wkv, bkv, outp, ws);
}